// Round 4
// baseline (319.415 us; speedup 1.0000x reference)
//
#include <hip/hip_runtime.h>
#include <hip/hip_bf16.h>
#include <stdint.h>
#include <stddef.h>

// ContrastiveLoss: N=4096, D=768.
// loss = mean_{ij} (1-g)*d2 + g*max(2-sqrt(d2),0)^2,
// d2 = sa[i]+sb[j]-2*dot(i,j)+2e-6*(ra[i]-rb[j])+768e-12 (clamped at 0).
// R6: fp8 e4m3 GEMM, k-permuted layout, XOR-8 LDS, fused epilogue. 135.5 us.
// R7 (FAILED 158.5) / R8 (FAILED 154.9): gt inside the K-loop -> any vmem in
//     flight across __syncthreads gets drained (vmcnt(0)+s_barrier); gt's
//     ~900cyc HBM latency lands on the barrier critical path. Never overlap
//     cold loads with a barriered K-loop in plain HIP.
// R9 (138.1 = wash): gt read directly in epilogue (overlaps other blocks'
//     MFMA via 4 blocks/CU). GEMM itself is now the dominant term (~780 TF,
//     78% of the fp8 m97-structure ceiling).
// R10 (this): MX-scaled MFMA. mfma_scale_f32_16x16x128_f8f6f4 (fp8 e4m3,
//     scale=0x7F=2^0 => bit-identical e4m3 GEMM) runs at ~4.7 PF ubench vs
//     ~2 PF for non-scaled fp8; m148 measured 1628 TF in this exact
//     128^2/2-barrier structure. One instruction covers K=128 = whole BKE
//     tile: MFMA count 64 -> 16 per tile, ds_reads unchanged (16 b128).
//     C/D layout is shape-determined (= current 16x16 mapping): epilogue
//     untouched. A/B frag: lane(row=lane&15, k=(lane>>4)*32+0..31) => needs
//     ORIGINAL k-order chunks 2q,2q+1 -> k-permutation deleted, prologue
//     stores linearly. Frag reads keep the proven chunk^(row&7) b128 algebra
//     (same per-16-lane conflict structure). launch_bounds (256,3) for the
//     af[4]+bf[4]+acc register set (no spill under 160-reg cap).
// Lesson log: R4 32x32 frags = structural 4-way conflict; R3 dbuf = spill;
//     WRITE_SIZE is the spill detector; only R2's LDS algebra measures 0.

#define NROWS 4096
#define DIM   768
#define BM    128
#define BN    128
#define BKE   128              // K elements per tile (128 B fp8 rows)
#define MARGIN 2.0f
#define EPSV   1e-6f
#define SC1    0x7F7F7F7F      // e8m0 127 = 2^0 in every byte lane

typedef float f32x4 __attribute__((ext_vector_type(4)));
typedef int   i32x4 __attribute__((ext_vector_type(4)));
typedef int   i32x8 __attribute__((ext_vector_type(8)));
typedef unsigned long long u64;
typedef unsigned char fp8_t;

// ---------------- prologue: fp8 cast + exact fp32 row sums (2048 blocks) ---
__global__ __launch_bounds__(256) void prologue_kernel(
    const float* __restrict__ A, const float* __restrict__ B,
    fp8_t* __restrict__ Af8, fp8_t* __restrict__ Bf8,
    float* __restrict__ sa, float* __restrict__ sb,
    float* __restrict__ ra, float* __restrict__ rb,
    float* __restrict__ out)
{
    const int tid  = threadIdx.x;
    const int wave = tid >> 6;
    const int lane = tid & 63;
    const int bx   = blockIdx.x;

    if (bx == 0 && tid == 0) out[0] = 0.0f;

    const int isB  = bx >= 1024;
    const int row  = (bx & 1023) * 4 + wave;
    const float* X = isB ? B : A;
    fp8_t* Xb      = isB ? Bf8 : Af8;
    float* sdst    = isB ? sb : sa;
    float* rdst    = isB ? rb : ra;

    const float4* xr = (const float4*)(X + (size_t)row * DIM);
    unsigned int* xb = (unsigned int*)(Xb + (size_t)row * DIM);

    float sum = 0.0f, sq = 0.0f;
    #pragma unroll
    for (int jb = 0; jb < 3; ++jb) {
        float4 v = xr[lane + 64 * jb];
        int pk = 0;
        pk = __builtin_amdgcn_cvt_pk_fp8_f32(v.x, v.y, pk, false);
        pk = __builtin_amdgcn_cvt_pk_fp8_f32(v.z, v.w, pk, true);
        xb[lane + 64 * jb] = (unsigned int)pk;   // linear k-order store
        sum += (v.x + v.y) + (v.z + v.w);
        sq  += v.x * v.x + v.y * v.y + v.z * v.z + v.w * v.w;
    }
    #pragma unroll
    for (int off = 32; off > 0; off >>= 1) {
        sum += __shfl_down(sum, off);
        sq  += __shfl_down(sq,  off);
    }
    if (lane == 0) { rdst[row] = sum; sdst[row] = sq; }
}

// ---------------- fused GEMM + loss (MX-fp8, K=128 per MFMA) ---------------
// 128x128 tile / 256 threads (4 waves x 64x64; 4x4 grid of 16x16x128 scaled
// MFMA, scale=1.0). BKE=128 LDS rows, single-buffered 32 KB, 2-barrier loop.
// Staging: LDS slot p of row r holds global chunk p^(r&7) [XOR-8, 16B].
// Frag read: lane(fr=lane&15, q=lane>>4) needs original chunks 2q,2q+1 of
// its row -> slots (2q)^(r&7), (2q+1)^(r&7); same conflict-free algebra as
// R2 (per-16-lane group: 8 distinct 4-bank groups x 2 rows = free 2-way).
__global__ __launch_bounds__(256, 3) void loss_kernel(
    const fp8_t* __restrict__ A, const fp8_t* __restrict__ B,
    const float* __restrict__ sa, const float* __restrict__ sb,
    const float* __restrict__ ra, const float* __restrict__ rb,
    const int* __restrict__ gt, float* __restrict__ out)
{
    __shared__ __align__(16) fp8_t As[BM * BKE];  // 16 KB
    __shared__ __align__(16) fp8_t Bs[BN * BKE];  // 16 KB

    const int tid  = threadIdx.x;
    const int wave = tid >> 6;
    const int lane = tid & 63;
    const int m0 = blockIdx.y * BM;
    const int n0 = blockIdx.x * BN;

    f32x4 acc[4][4] = {};

    const int fr = lane & 15;            // frag row (A) / frag col (B)
    const int q  = lane >> 4;            // quad: k-block (lane>>4)*32
    const int wm = (wave >> 1) * 64;
    const int wn = (wave & 1) * 64;

    const int srow = lane >> 3;
    const int sp   = lane & 7;

    for (int k0 = 0; k0 < DIM; k0 += BKE) {
        __syncthreads();   // prev iter's LDS reads done
        #pragma unroll
        for (int j = 0; j < 4; ++j) {          // A: 1024 chunks, 256/wave
            const int c0  = wave * 256 + j * 64;            // wave-uniform
            const int row = (c0 >> 3) + srow;
            const int gcx = sp ^ (row & 7);
            const fp8_t* ga = A + (size_t)(m0 + row) * DIM + k0 + gcx * 16;
            __builtin_amdgcn_global_load_lds(
                (const __attribute__((address_space(1))) void*)ga,
                (__attribute__((address_space(3))) void*)(As + c0 * 16),
                16, 0, 0);
        }
        #pragma unroll
        for (int j = 0; j < 4; ++j) {          // B: 1024 chunks, 256/wave
            const int c0  = wave * 256 + j * 64;
            const int row = (c0 >> 3) + srow;
            const int gcx = sp ^ (row & 7);
            const fp8_t* gb = B + (size_t)(n0 + row) * DIM + k0 + gcx * 16;
            __builtin_amdgcn_global_load_lds(
                (const __attribute__((address_space(1))) void*)gb,
                (__attribute__((address_space(3))) void*)(Bs + c0 * 16),
                16, 0, 0);
        }
        __syncthreads();   // staging complete

        // fragment reads: 2x b128 per operand-row (original chunks 2q,2q+1)
        i32x8 af[4], bf[4];
        #pragma unroll
        for (int i = 0; i < 4; ++i) {
            const int ar = wm + i * 16 + fr;
            const i32x4 lo =
                *(const i32x4*)(As + ar * BKE + (((2 * q)     ^ (ar & 7)) * 16));
            const i32x4 hi =
                *(const i32x4*)(As + ar * BKE + (((2 * q + 1) ^ (ar & 7)) * 16));
            af[i] = __builtin_shufflevector(lo, hi, 0, 1, 2, 3, 4, 5, 6, 7);
        }
        #pragma unroll
        for (int i = 0; i < 4; ++i) {
            const int br = wn + i * 16 + fr;
            const i32x4 lo =
                *(const i32x4*)(Bs + br * BKE + (((2 * q)     ^ (br & 7)) * 16));
            const i32x4 hi =
                *(const i32x4*)(Bs + br * BKE + (((2 * q + 1) ^ (br & 7)) * 16));
            bf[i] = __builtin_shufflevector(lo, hi, 0, 1, 2, 3, 4, 5, 6, 7);
        }

        // 16 scaled MFMAs, K=128 each (whole tile), scale = 2^0 exact
        #pragma unroll
        for (int mi = 0; mi < 4; ++mi)
            #pragma unroll
            for (int ni = 0; ni < 4; ++ni)
                acc[mi][ni] = __builtin_amdgcn_mfma_scale_f32_16x16x128_f8f6f4(
                    af[mi], bf[ni], acc[mi][ni], 0, 0, 0, SC1, 0, SC1);
    }

    // ---- fused epilogue: C/D col=lane&15, row=(lane>>4)*4+reg ----
    // (shape-determined layout: identical for the f8f6f4-scaled 16x16 MFMA)
    const int cq = lane & 15;
    const int rq = (lane >> 4) * 4;

    float cc[4];
    #pragma unroll
    for (int ni = 0; ni < 4; ++ni) {
        const int col = n0 + wn + ni * 16 + cq;
        cc[ni] = sb[col] - 2.0f * EPSV * rb[col];
    }

    float local = 0.0f;
    #pragma unroll
    for (int mi = 0; mi < 4; ++mi) {
        #pragma unroll
        for (int rr = 0; rr < 4; ++rr) {
            const int row = m0 + wm + mi * 16 + rq + rr;
            const float crr = sa[row] + 2.0f * EPSV * ra[row]
                            + (float)DIM * EPSV * EPSV;
            const int* gr = gt + (size_t)row * NROWS + n0 + wn + cq;
            int gvals[4];
            #pragma unroll
            for (int ni = 0; ni < 4; ++ni) gvals[ni] = gr[ni * 16];
            #pragma unroll
            for (int ni = 0; ni < 4; ++ni) {
                const float d2 = (crr + cc[ni]) - 2.0f * acc[mi][ni][rr];
                const float gf = (gvals[ni] != 0) ? 1.0f : 0.0f;
                float contrib = d2 - gf * d2;           // hinge==0 fast path
                if (__builtin_expect(d2 < 4.0f, 0)) {   // exact, never taken
                    const float d2c  = fmaxf(d2, 0.0f);
                    const float dist = sqrtf(d2c);
                    const float h    = fmaxf(MARGIN - dist, 0.0f);
                    contrib = (1.0f - gf) * d2c + gf * h * h;
                }
                local += contrib;
            }
        }
    }

    #pragma unroll
    for (int off = 32; off > 0; off >>= 1) local += __shfl_down(local, off);

    float* redp = (float*)As;   // reuse LDS for block reduction
    __syncthreads();
    if (lane == 0) redp[wave] = local;
    __syncthreads();
    if (tid == 0) {
        const float s = (redp[0] + redp[1]) + (redp[2] + redp[3]);
        atomicAdd(out, s * (1.0f / (4096.0f * 4096.0f)));
    }
}

// ---------------------------------------------------------------------------
extern "C" void kernel_launch(void* const* d_in, const int* in_sizes, int n_in,
                              void* d_out, int out_size, void* d_ws, size_t ws_size,
                              hipStream_t stream)
{
    const float* A  = (const float*)d_in[0];
    const float* B  = (const float*)d_in[1];
    const int*   gt = (const int*)d_in[2];
    float* out = (float*)d_out;

    char* ws = (char*)d_ws;
    const size_t NB8 = (size_t)NROWS * DIM;   // 3,145,728 B per fp8 matrix
    fp8_t* Af8 = (fp8_t*)(ws);
    fp8_t* Bf8 = (fp8_t*)(ws + NB8);
    float* sa = (float*)(ws + 2 * NB8);
    float* sb = (float*)(ws + 2 * NB8 + 16384);
    float* ra = (float*)(ws + 2 * NB8 + 32768);
    float* rb = (float*)(ws + 2 * NB8 + 49152);

    prologue_kernel<<<dim3(2048), 256, 0, stream>>>(
        A, B, Af8, Bf8, sa, sb, ra, rb, out);
    loss_kernel<<<dim3(NROWS / BN, NROWS / BM), 256, 0, stream>>>(
        Af8, Bf8, sa, sb, ra, rb, gt, out);
}

// Round 5
// 307.780 us; speedup vs baseline: 1.0378x; 1.0378x over previous
//
#include <hip/hip_runtime.h>
#include <hip/hip_bf16.h>
#include <stdint.h>
#include <stddef.h>

// ContrastiveLoss: N=4096, D=768.
// loss = mean_{ij} (1-g)*d2 + g*max(2-sqrt(d2),0)^2,
// d2 = sa[i]+sb[j]-2*dot(i,j)+2e-6*(ra[i]-rb[j])+768e-12 (clamped at 0).
// R6:  fp8 GEMM, XOR-8 LDS, fused epilogue. 135.5 us (best fp8).
// R7/R8 (FAILED): gt in the K-loop -> __syncthreads drains in-flight vmem;
//      cold-HBM gt latency lands on the barrier critical path.
// R9 (138.1): gt direct in epilogue; GEMM dominates (~780 TF fp8).
// R10 (FAILED 319): MX-scaled 16x16x128 MFMA with 4x4 acc/wave. absmax=0
//      (math+layout VERIFIED) but live set ~150 regs vs VGPR_Count 84 ->
//      scratch spill in K-loop: WRITE_SIZE 277 MB, FETCH 347 MB, MfmaUtil 2%.
// R11 (this): same MX math, register-sized structure: 8 waves (512 thr) per
//      128^2 block, 32x64 per wave -> acc 32 + af[2] 16 + bf[4] 32 ~= 100
//      live < 128-reg cap of launch_bounds(512,4) (2 blocks/CU, 16 waves/CU,
//      same occupancy regime as R6). Staging/frag/epilogue algebra unchanged,
//      just re-divided among 8 waves. GEMM floor ~16 us (m148: 1628 TF).
// Lesson log: R4 32x32 frags = structural 4-way LDS conflict; R3 dbuf =
//      spill; WRITE_SIZE is the spill detector; only R2's LDS algebra
//      measures 0 conflicts; R7/R8: never leave vmem in flight across
//      __syncthreads; R10: MX 8-reg operands + 64-reg acc don't fit one wave.

#define NROWS 4096
#define DIM   768
#define BM    128
#define BN    128
#define BKE   128              // K elements per tile (128 B fp8 rows)
#define MARGIN 2.0f
#define EPSV   1e-6f
#define SC1    0x7F7F7F7F      // e8m0 127 = 2^0 in every byte lane

typedef float f32x4 __attribute__((ext_vector_type(4)));
typedef int   i32x4 __attribute__((ext_vector_type(4)));
typedef int   i32x8 __attribute__((ext_vector_type(8)));
typedef unsigned long long u64;
typedef unsigned char fp8_t;

// ---------------- prologue: fp8 cast + exact fp32 row sums (2048 blocks) ---
__global__ __launch_bounds__(256) void prologue_kernel(
    const float* __restrict__ A, const float* __restrict__ B,
    fp8_t* __restrict__ Af8, fp8_t* __restrict__ Bf8,
    float* __restrict__ sa, float* __restrict__ sb,
    float* __restrict__ ra, float* __restrict__ rb,
    float* __restrict__ out)
{
    const int tid  = threadIdx.x;
    const int wave = tid >> 6;
    const int lane = tid & 63;
    const int bx   = blockIdx.x;

    if (bx == 0 && tid == 0) out[0] = 0.0f;

    const int isB  = bx >= 1024;
    const int row  = (bx & 1023) * 4 + wave;
    const float* X = isB ? B : A;
    fp8_t* Xb      = isB ? Bf8 : Af8;
    float* sdst    = isB ? sb : sa;
    float* rdst    = isB ? rb : ra;

    const float4* xr = (const float4*)(X + (size_t)row * DIM);
    unsigned int* xb = (unsigned int*)(Xb + (size_t)row * DIM);

    float sum = 0.0f, sq = 0.0f;
    #pragma unroll
    for (int jb = 0; jb < 3; ++jb) {
        float4 v = xr[lane + 64 * jb];
        int pk = 0;
        pk = __builtin_amdgcn_cvt_pk_fp8_f32(v.x, v.y, pk, false);
        pk = __builtin_amdgcn_cvt_pk_fp8_f32(v.z, v.w, pk, true);
        xb[lane + 64 * jb] = (unsigned int)pk;   // linear k-order store
        sum += (v.x + v.y) + (v.z + v.w);
        sq  += v.x * v.x + v.y * v.y + v.z * v.z + v.w * v.w;
    }
    #pragma unroll
    for (int off = 32; off > 0; off >>= 1) {
        sum += __shfl_down(sum, off);
        sq  += __shfl_down(sq,  off);
    }
    if (lane == 0) { rdst[row] = sum; sdst[row] = sq; }
}

// ---------------- fused GEMM + loss (MX-fp8, K=128 per MFMA) ---------------
// 128x128 tile / 512 threads / 8 waves; wave (wr=wave>>1, wc=wave&1) owns a
// 32x64 sub-tile at (wr*32, wc*64): 2x4 grid of 16x16x128 scaled MFMAs
// (scale=2^0 => bit-exact e4m3 GEMM; verified absmax=0 in R10).
// Staging: LDS slot p of row r holds global chunk p^(r&7) [XOR-8, 16B].
// Frag read: lane(fr=lane&15, q=lane>>4) reads original chunks 2q,2q+1 of
// its row at slots (2q)^(r&7),(2q+1)^(r&7) -- per-16-lane group: 8 distinct
// 4-bank groups x 2 rows = free 2-way (R2/R6's measured-zero algebra).
__global__ __launch_bounds__(512, 4) void loss_kernel(
    const fp8_t* __restrict__ A, const fp8_t* __restrict__ B,
    const float* __restrict__ sa, const float* __restrict__ sb,
    const float* __restrict__ ra, const float* __restrict__ rb,
    const int* __restrict__ gt, float* __restrict__ out)
{
    __shared__ __align__(16) fp8_t As[BM * BKE];  // 16 KB
    __shared__ __align__(16) fp8_t Bs[BN * BKE];  // 16 KB

    const int tid  = threadIdx.x;
    const int wave = tid >> 6;
    const int lane = tid & 63;
    const int m0 = blockIdx.y * BM;
    const int n0 = blockIdx.x * BN;

    f32x4 acc[2][4] = {};

    const int fr = lane & 15;            // frag row (A) / frag col (B)
    const int q  = lane >> 4;            // quad: k-block (lane>>4)*32
    const int wm = (wave >> 1) * 32;     // wave row band (0,32,64,96)
    const int wn = (wave & 1) * 64;      // wave col band (0,64)

    const int srow = lane >> 3;
    const int sp   = lane & 7;

    for (int k0 = 0; k0 < DIM; k0 += BKE) {
        __syncthreads();   // prev iter's LDS reads done
        #pragma unroll
        for (int j = 0; j < 2; ++j) {          // A: 1024 chunks, 128/wave
            const int c0  = wave * 128 + j * 64;            // wave-uniform
            const int row = (c0 >> 3) + srow;
            const int gcx = sp ^ (row & 7);
            const fp8_t* ga = A + (size_t)(m0 + row) * DIM + k0 + gcx * 16;
            __builtin_amdgcn_global_load_lds(
                (const __attribute__((address_space(1))) void*)ga,
                (__attribute__((address_space(3))) void*)(As + c0 * 16),
                16, 0, 0);
        }
        #pragma unroll
        for (int j = 0; j < 2; ++j) {          // B: 1024 chunks, 128/wave
            const int c0  = wave * 128 + j * 64;
            const int row = (c0 >> 3) + srow;
            const int gcx = sp ^ (row & 7);
            const fp8_t* gb = B + (size_t)(n0 + row) * DIM + k0 + gcx * 16;
            __builtin_amdgcn_global_load_lds(
                (const __attribute__((address_space(1))) void*)gb,
                (__attribute__((address_space(3))) void*)(Bs + c0 * 16),
                16, 0, 0);
        }
        __syncthreads();   // staging complete

        // fragment reads: 2x b128 per operand-row (original chunks 2q,2q+1)
        i32x8 af[2], bf[4];
        #pragma unroll
        for (int i = 0; i < 2; ++i) {
            const int ar = wm + i * 16 + fr;
            const i32x4 lo =
                *(const i32x4*)(As + ar * BKE + (((2 * q)     ^ (ar & 7)) * 16));
            const i32x4 hi =
                *(const i32x4*)(As + ar * BKE + (((2 * q + 1) ^ (ar & 7)) * 16));
            af[i] = __builtin_shufflevector(lo, hi, 0, 1, 2, 3, 4, 5, 6, 7);
        }
        #pragma unroll
        for (int i = 0; i < 4; ++i) {
            const int br = wn + i * 16 + fr;
            const i32x4 lo =
                *(const i32x4*)(Bs + br * BKE + (((2 * q)     ^ (br & 7)) * 16));
            const i32x4 hi =
                *(const i32x4*)(Bs + br * BKE + (((2 * q + 1) ^ (br & 7)) * 16));
            bf[i] = __builtin_shufflevector(lo, hi, 0, 1, 2, 3, 4, 5, 6, 7);
        }

        // 8 scaled MFMAs, K=128 each (whole tile), scale = 2^0 exact
        #pragma unroll
        for (int mi = 0; mi < 2; ++mi)
            #pragma unroll
            for (int ni = 0; ni < 4; ++ni)
                acc[mi][ni] = __builtin_amdgcn_mfma_scale_f32_16x16x128_f8f6f4(
                    af[mi], bf[ni], acc[mi][ni], 0, 0, 0, SC1, 0, SC1);
    }

    // ---- fused epilogue: C/D col=lane&15, row=(lane>>4)*4+reg ----
    // (shape-determined layout, verified absmax=0 in R10)
    const int cq = lane & 15;
    const int rq = (lane >> 4) * 4;

    float cc[4];
    #pragma unroll
    for (int ni = 0; ni < 4; ++ni) {
        const int col = n0 + wn + ni * 16 + cq;
        cc[ni] = sb[col] - 2.0f * EPSV * rb[col];
    }

    float local = 0.0f;
    #pragma unroll
    for (int mi = 0; mi < 2; ++mi) {
        #pragma unroll
        for (int rr = 0; rr < 4; ++rr) {
            const int row = m0 + wm + mi * 16 + rq + rr;
            const float crr = sa[row] + 2.0f * EPSV * ra[row]
                            + (float)DIM * EPSV * EPSV;
            const int* gr = gt + (size_t)row * NROWS + n0 + wn + cq;
            int gvals[4];
            #pragma unroll
            for (int ni = 0; ni < 4; ++ni) gvals[ni] = gr[ni * 16];
            #pragma unroll
            for (int ni = 0; ni < 4; ++ni) {
                const float d2 = (crr + cc[ni]) - 2.0f * acc[mi][ni][rr];
                const float gf = (gvals[ni] != 0) ? 1.0f : 0.0f;
                float contrib = d2 - gf * d2;           // hinge==0 fast path
                if (__builtin_expect(d2 < 4.0f, 0)) {   // exact, never taken
                    const float d2c  = fmaxf(d2, 0.0f);
                    const float dist = sqrtf(d2c);
                    const float h    = fmaxf(MARGIN - dist, 0.0f);
                    contrib = (1.0f - gf) * d2c + gf * h * h;
                }
                local += contrib;
            }
        }
    }

    #pragma unroll
    for (int off = 32; off > 0; off >>= 1) local += __shfl_down(local, off);

    float* redp = (float*)As;   // reuse LDS for block reduction (8 floats)
    __syncthreads();
    if (lane == 0) redp[wave] = local;
    __syncthreads();
    if (tid == 0) {
        float s = 0.0f;
        #pragma unroll
        for (int w = 0; w < 8; ++w) s += redp[w];
        atomicAdd(out, s * (1.0f / (4096.0f * 4096.0f)));
    }
}

// ---------------------------------------------------------------------------
extern "C" void kernel_launch(void* const* d_in, const int* in_sizes, int n_in,
                              void* d_out, int out_size, void* d_ws, size_t ws_size,
                              hipStream_t stream)
{
    const float* A  = (const float*)d_in[0];
    const float* B  = (const float*)d_in[1];
    const int*   gt = (const int*)d_in[2];
    float* out = (float*)d_out;

    char* ws = (char*)d_ws;
    const size_t NB8 = (size_t)NROWS * DIM;   // 3,145,728 B per fp8 matrix
    fp8_t* Af8 = (fp8_t*)(ws);
    fp8_t* Bf8 = (fp8_t*)(ws + NB8);
    float* sa = (float*)(ws + 2 * NB8);
    float* sb = (float*)(ws + 2 * NB8 + 16384);
    float* ra = (float*)(ws + 2 * NB8 + 32768);
    float* rb = (float*)(ws + 2 * NB8 + 49152);

    prologue_kernel<<<dim3(2048), 256, 0, stream>>>(
        A, B, Af8, Bf8, sa, sb, ra, rb, out);
    loss_kernel<<<dim3(NROWS / BN, NROWS / BM), 512, 0, stream>>>(
        Af8, Bf8, sa, sb, ra, rb, gt, out);
}

// Round 6
// 229.698 us; speedup vs baseline: 1.3906x; 1.3399x over previous
//
#include <hip/hip_runtime.h>
#include <hip/hip_bf16.h>
#include <stdint.h>
#include <stddef.h>

// ContrastiveLoss: N=4096, D=768.
// loss = mean_{ij} (1-g)*d2 + g*max(2-sqrt(d2),0)^2,
// d2 = sa[i]+sb[j]-2*dot(i,j)+2e-6*(ra[i]-rb[j])+768e-12 (clamped at 0).
// R6:  fp8 GEMM, XOR-8 LDS, fused epilogue. 135.5 us (best fp8).
// R7/R8 (FAILED): gt in the K-loop -> __syncthreads drains in-flight vmem.
// R9 (138.1): gt direct in epilogue; GEMM dominates (~780 TF fp8).
// R10 (FAILED 319): MX 16x16x128, 4 waves, 4x4 acc. absmax=0 (math+layout
//      VERIFIED) but launch_bounds(256,3) caps total regs at ~170 < demand
//      (arch ~100 for af[4]+bf[4] tuples + temps, accum 64) -> K-loop spill:
//      WRITE 277 MB, MfmaUtil 2%.
// R11 (FAILED 308): (512,4) cap 128 — even tighter. WRITE 420 MB. Both
//      failures were the BOUND, not the structure: VGPR_Count=64 arch shows
//      the allocator starved at the cap while accum held 64.
// R12 (this): R10 verbatim with launch_bounds(256,2) — cap 256, allocator
//      takes ~170. Occupancy 2 blocks/CU (8 waves/CU) = m148's measured
//      regime (1628 TF for MX-fp8 K=128 in this exact 128^2 structure).
// Lesson log: R4 32x32 frags = structural LDS conflict; R3 dbuf = spill;
//      WRITE_SIZE is the spill detector; R7/R8: never leave vmem in flight
//      across __syncthreads; R10/R11: MX needs ~170 regs — never cap below
//      (256,2) with 8-reg MFMA operands + 64-reg accum.

#define NROWS 4096
#define DIM   768
#define BM    128
#define BN    128
#define BKE   128              // K elements per tile (128 B fp8 rows)
#define MARGIN 2.0f
#define EPSV   1e-6f
#define SC1    0x7F7F7F7F      // e8m0 127 = 2^0 in every byte lane

typedef float f32x4 __attribute__((ext_vector_type(4)));
typedef int   i32x4 __attribute__((ext_vector_type(4)));
typedef int   i32x8 __attribute__((ext_vector_type(8)));
typedef unsigned long long u64;
typedef unsigned char fp8_t;

// ---------------- prologue: fp8 cast + exact fp32 row sums (2048 blocks) ---
__global__ __launch_bounds__(256) void prologue_kernel(
    const float* __restrict__ A, const float* __restrict__ B,
    fp8_t* __restrict__ Af8, fp8_t* __restrict__ Bf8,
    float* __restrict__ sa, float* __restrict__ sb,
    float* __restrict__ ra, float* __restrict__ rb,
    float* __restrict__ out)
{
    const int tid  = threadIdx.x;
    const int wave = tid >> 6;
    const int lane = tid & 63;
    const int bx   = blockIdx.x;

    if (bx == 0 && tid == 0) out[0] = 0.0f;

    const int isB  = bx >= 1024;
    const int row  = (bx & 1023) * 4 + wave;
    const float* X = isB ? B : A;
    fp8_t* Xb      = isB ? Bf8 : Af8;
    float* sdst    = isB ? sb : sa;
    float* rdst    = isB ? rb : ra;

    const float4* xr = (const float4*)(X + (size_t)row * DIM);
    unsigned int* xb = (unsigned int*)(Xb + (size_t)row * DIM);

    float sum = 0.0f, sq = 0.0f;
    #pragma unroll
    for (int jb = 0; jb < 3; ++jb) {
        float4 v = xr[lane + 64 * jb];
        int pk = 0;
        pk = __builtin_amdgcn_cvt_pk_fp8_f32(v.x, v.y, pk, false);
        pk = __builtin_amdgcn_cvt_pk_fp8_f32(v.z, v.w, pk, true);
        xb[lane + 64 * jb] = (unsigned int)pk;   // linear k-order store
        sum += (v.x + v.y) + (v.z + v.w);
        sq  += v.x * v.x + v.y * v.y + v.z * v.z + v.w * v.w;
    }
    #pragma unroll
    for (int off = 32; off > 0; off >>= 1) {
        sum += __shfl_down(sum, off);
        sq  += __shfl_down(sq,  off);
    }
    if (lane == 0) { rdst[row] = sum; sdst[row] = sq; }
}

// ---------------- fused GEMM + loss (MX-fp8, K=128 per MFMA) ---------------
// 128x128 tile / 256 threads (4 waves x 64x64; 4x4 grid of 16x16x128 scaled
// MFMA, scale=2^0 => bit-exact e4m3 GEMM; verified absmax=0 in R10/R11).
// Staging: LDS slot p of row r holds global chunk p^(r&7) [XOR-8, 16B].
// Frag read: lane(fr=lane&15, q=lane>>4) needs original chunks 2q,2q+1 of
// its row -> slots (2q)^(r&7),(2q+1)^(r&7); per-16-lane group: 8 distinct
// 4-bank groups x 2 rows = free 2-way (R2/R6's measured-zero algebra).
// launch_bounds(256,2): cap 256 regs — the MX reg set (~170: af/bf 64 arch
// tuple + temps, 64 accum) MUST NOT be capped tighter (R10/R11 lesson).
__global__ __launch_bounds__(256, 2) void loss_kernel(
    const fp8_t* __restrict__ A, const fp8_t* __restrict__ B,
    const float* __restrict__ sa, const float* __restrict__ sb,
    const float* __restrict__ ra, const float* __restrict__ rb,
    const int* __restrict__ gt, float* __restrict__ out)
{
    __shared__ __align__(16) fp8_t As[BM * BKE];  // 16 KB
    __shared__ __align__(16) fp8_t Bs[BN * BKE];  // 16 KB

    const int tid  = threadIdx.x;
    const int wave = tid >> 6;
    const int lane = tid & 63;
    const int m0 = blockIdx.y * BM;
    const int n0 = blockIdx.x * BN;

    f32x4 acc[4][4] = {};

    const int fr = lane & 15;            // frag row (A) / frag col (B)
    const int q  = lane >> 4;            // quad: k-block (lane>>4)*32
    const int wm = (wave >> 1) * 64;
    const int wn = (wave & 1) * 64;

    const int srow = lane >> 3;
    const int sp   = lane & 7;

    for (int k0 = 0; k0 < DIM; k0 += BKE) {
        __syncthreads();   // prev iter's LDS reads done
        #pragma unroll
        for (int j = 0; j < 4; ++j) {          // A: 1024 chunks, 256/wave
            const int c0  = wave * 256 + j * 64;            // wave-uniform
            const int row = (c0 >> 3) + srow;
            const int gcx = sp ^ (row & 7);
            const fp8_t* ga = A + (size_t)(m0 + row) * DIM + k0 + gcx * 16;
            __builtin_amdgcn_global_load_lds(
                (const __attribute__((address_space(1))) void*)ga,
                (__attribute__((address_space(3))) void*)(As + c0 * 16),
                16, 0, 0);
        }
        #pragma unroll
        for (int j = 0; j < 4; ++j) {          // B: 1024 chunks, 256/wave
            const int c0  = wave * 256 + j * 64;
            const int row = (c0 >> 3) + srow;
            const int gcx = sp ^ (row & 7);
            const fp8_t* gb = B + (size_t)(n0 + row) * DIM + k0 + gcx * 16;
            __builtin_amdgcn_global_load_lds(
                (const __attribute__((address_space(1))) void*)gb,
                (__attribute__((address_space(3))) void*)(Bs + c0 * 16),
                16, 0, 0);
        }
        __syncthreads();   // staging complete

        // fragment reads: 2x b128 per operand-row (original chunks 2q,2q+1)
        i32x8 af[4], bf[4];
        #pragma unroll
        for (int i = 0; i < 4; ++i) {
            const int ar = wm + i * 16 + fr;
            const i32x4 lo =
                *(const i32x4*)(As + ar * BKE + (((2 * q)     ^ (ar & 7)) * 16));
            const i32x4 hi =
                *(const i32x4*)(As + ar * BKE + (((2 * q + 1) ^ (ar & 7)) * 16));
            af[i] = __builtin_shufflevector(lo, hi, 0, 1, 2, 3, 4, 5, 6, 7);
        }
        #pragma unroll
        for (int i = 0; i < 4; ++i) {
            const int br = wn + i * 16 + fr;
            const i32x4 lo =
                *(const i32x4*)(Bs + br * BKE + (((2 * q)     ^ (br & 7)) * 16));
            const i32x4 hi =
                *(const i32x4*)(Bs + br * BKE + (((2 * q + 1) ^ (br & 7)) * 16));
            bf[i] = __builtin_shufflevector(lo, hi, 0, 1, 2, 3, 4, 5, 6, 7);
        }

        // 16 scaled MFMAs, K=128 each (whole tile), scale = 2^0 exact
        #pragma unroll
        for (int mi = 0; mi < 4; ++mi)
            #pragma unroll
            for (int ni = 0; ni < 4; ++ni)
                acc[mi][ni] = __builtin_amdgcn_mfma_scale_f32_16x16x128_f8f6f4(
                    af[mi], bf[ni], acc[mi][ni], 0, 0, 0, SC1, 0, SC1);
    }

    // ---- fused epilogue: C/D col=lane&15, row=(lane>>4)*4+reg ----
    // (shape-determined layout, verified absmax=0 in R10/R11)
    const int cq = lane & 15;
    const int rq = (lane >> 4) * 4;

    float cc[4];
    #pragma unroll
    for (int ni = 0; ni < 4; ++ni) {
        const int col = n0 + wn + ni * 16 + cq;
        cc[ni] = sb[col] - 2.0f * EPSV * rb[col];
    }

    float local = 0.0f;
    #pragma unroll
    for (int mi = 0; mi < 4; ++mi) {
        #pragma unroll
        for (int rr = 0; rr < 4; ++rr) {
            const int row = m0 + wm + mi * 16 + rq + rr;
            const float crr = sa[row] + 2.0f * EPSV * ra[row]
                            + (float)DIM * EPSV * EPSV;
            const int* gr = gt + (size_t)row * NROWS + n0 + wn + cq;
            int gvals[4];
            #pragma unroll
            for (int ni = 0; ni < 4; ++ni) gvals[ni] = gr[ni * 16];
            #pragma unroll
            for (int ni = 0; ni < 4; ++ni) {
                const float d2 = (crr + cc[ni]) - 2.0f * acc[mi][ni][rr];
                const float gf = (gvals[ni] != 0) ? 1.0f : 0.0f;
                float contrib = d2 - gf * d2;           // hinge==0 fast path
                if (__builtin_expect(d2 < 4.0f, 0)) {   // exact, never taken
                    const float d2c  = fmaxf(d2, 0.0f);
                    const float dist = sqrtf(d2c);
                    const float h    = fmaxf(MARGIN - dist, 0.0f);
                    contrib = (1.0f - gf) * d2c + gf * h * h;
                }
                local += contrib;
            }
        }
    }

    #pragma unroll
    for (int off = 32; off > 0; off >>= 1) local += __shfl_down(local, off);

    float* redp = (float*)As;   // reuse LDS for block reduction
    __syncthreads();
    if (lane == 0) redp[wave] = local;
    __syncthreads();
    if (tid == 0) {
        const float s = (redp[0] + redp[1]) + (redp[2] + redp[3]);
        atomicAdd(out, s * (1.0f / (4096.0f * 4096.0f)));
    }
}

// ---------------------------------------------------------------------------
extern "C" void kernel_launch(void* const* d_in, const int* in_sizes, int n_in,
                              void* d_out, int out_size, void* d_ws, size_t ws_size,
                              hipStream_t stream)
{
    const float* A  = (const float*)d_in[0];
    const float* B  = (const float*)d_in[1];
    const int*   gt = (const int*)d_in[2];
    float* out = (float*)d_out;

    char* ws = (char*)d_ws;
    const size_t NB8 = (size_t)NROWS * DIM;   // 3,145,728 B per fp8 matrix
    fp8_t* Af8 = (fp8_t*)(ws);
    fp8_t* Bf8 = (fp8_t*)(ws + NB8);
    float* sa = (float*)(ws + 2 * NB8);
    float* sb = (float*)(ws + 2 * NB8 + 16384);
    float* ra = (float*)(ws + 2 * NB8 + 32768);
    float* rb = (float*)(ws + 2 * NB8 + 49152);

    prologue_kernel<<<dim3(2048), 256, 0, stream>>>(
        A, B, Af8, Bf8, sa, sb, ra, rb, out);
    loss_kernel<<<dim3(NROWS / BN, NROWS / BM), 256, 0, stream>>>(
        Af8, Bf8, sa, sb, ra, rb, gt, out);
}

// Round 7
// 172.278 us; speedup vs baseline: 1.8541x; 1.3333x over previous
//
#include <hip/hip_runtime.h>
#include <hip/hip_bf16.h>
#include <stdint.h>
#include <stddef.h>

// ContrastiveLoss: N=4096, D=768.
// loss = mean_{ij} (1-g)*d2 + g*max(2-sqrt(d2),0)^2,
// d2 = sa[i]+sb[j]-2*dot(i,j)+2e-6*(ra[i]-rb[j])+768e-12 (clamped at 0).
// R6:  fp8 GEMM, XOR-8 LDS, fused epilogue. 135.5 us (best known).
// R7/R8 (FAILED): gt in the K-loop -> __syncthreads drains in-flight vmem.
// R9 (138.1): gt direct in epilogue; GEMM dominates (~780 TF fp8).
// R10-R12 (FAILED 319/308/230): MX 16x16x128 spills. Cap ladder: 170-cap ->
//      277 MB spill, 128-cap -> 420 MB, 256-cap -> 139 MB @ VGPR 128+64acc.
//      Cause: af[4]+bf[4] = 64 operand regs live AT ONCE + 64 acc + temps
//      ~= 200 peak. Math/layout verified (absmax=0 all three rounds).
// R13 (this): (1) peak-liveness fix: load bf[4] once (32 regs), then per-mi
//      load ONE a-frag (8 regs) and fire its 4 MFMAs -> peak ~125 regs.
//      (2) UNCAPPED launch_bounds(256): capping was the proven failure mode;
//      allocator sizes freely (~140-170 -> 3 waves/EU, m97/m148 regime).
//      Pre-committed failure criterion: WRITE_SIZE>1MB or loss>45us -> MX
//      dead, revert R6.
// Lesson log: R4 32x32 frags = structural LDS conflict; R3 dbuf = spill;
//      WRITE_SIZE is the spill detector; R7/R8: never leave vmem in flight
//      across __syncthreads; R10-R12: never cap regs on 8-reg-operand MFMA
//      kernels, and never hold two 4-frag operand arrays live at once.

#define NROWS 4096
#define DIM   768
#define BM    128
#define BN    128
#define BKE   128              // K elements per tile (128 B fp8 rows)
#define MARGIN 2.0f
#define EPSV   1e-6f
#define SC1    0x7F7F7F7F      // e8m0 127 = 2^0 in every byte lane

typedef float f32x4 __attribute__((ext_vector_type(4)));
typedef int   i32x4 __attribute__((ext_vector_type(4)));
typedef int   i32x8 __attribute__((ext_vector_type(8)));
typedef unsigned long long u64;
typedef unsigned char fp8_t;

// ---------------- prologue: fp8 cast + exact fp32 row sums (2048 blocks) ---
__global__ __launch_bounds__(256) void prologue_kernel(
    const float* __restrict__ A, const float* __restrict__ B,
    fp8_t* __restrict__ Af8, fp8_t* __restrict__ Bf8,
    float* __restrict__ sa, float* __restrict__ sb,
    float* __restrict__ ra, float* __restrict__ rb,
    float* __restrict__ out)
{
    const int tid  = threadIdx.x;
    const int wave = tid >> 6;
    const int lane = tid & 63;
    const int bx   = blockIdx.x;

    if (bx == 0 && tid == 0) out[0] = 0.0f;

    const int isB  = bx >= 1024;
    const int row  = (bx & 1023) * 4 + wave;
    const float* X = isB ? B : A;
    fp8_t* Xb      = isB ? Bf8 : Af8;
    float* sdst    = isB ? sb : sa;
    float* rdst    = isB ? rb : ra;

    const float4* xr = (const float4*)(X + (size_t)row * DIM);
    unsigned int* xb = (unsigned int*)(Xb + (size_t)row * DIM);

    float sum = 0.0f, sq = 0.0f;
    #pragma unroll
    for (int jb = 0; jb < 3; ++jb) {
        float4 v = xr[lane + 64 * jb];
        int pk = 0;
        pk = __builtin_amdgcn_cvt_pk_fp8_f32(v.x, v.y, pk, false);
        pk = __builtin_amdgcn_cvt_pk_fp8_f32(v.z, v.w, pk, true);
        xb[lane + 64 * jb] = (unsigned int)pk;   // linear k-order store
        sum += (v.x + v.y) + (v.z + v.w);
        sq  += v.x * v.x + v.y * v.y + v.z * v.z + v.w * v.w;
    }
    #pragma unroll
    for (int off = 32; off > 0; off >>= 1) {
        sum += __shfl_down(sum, off);
        sq  += __shfl_down(sq,  off);
    }
    if (lane == 0) { rdst[row] = sum; sdst[row] = sq; }
}

// ---------------- fused GEMM + loss (MX-fp8, K=128 per MFMA) ---------------
// 128x128 tile / 256 threads (4 waves x 64x64; 4x4 grid of 16x16x128 scaled
// MFMA, scale=2^0 => bit-exact e4m3 GEMM; verified absmax=0 R10-R12).
// Staging: LDS slot p of row r holds global chunk p^(r&7) [XOR-8, 16B].
// Frag read: lane(fr=lane&15, q=lane>>4) needs original chunks 2q,2q+1 of
// its row -> slots (2q)^(r&7),(2q+1)^(r&7); any 8 consecutive lanes cover 8
// distinct 16B slots = all 32 banks once (R2/R6 conflict-free algebra).
// Register schedule (the R13 fix): bf[4] loaded once (32 regs); per mi, ONE
// a-frag (8 regs) then its 4 MFMAs -> peak live ~125. UNCAPPED bounds.
__global__ __launch_bounds__(256) void loss_kernel(
    const fp8_t* __restrict__ A, const fp8_t* __restrict__ B,
    const float* __restrict__ sa, const float* __restrict__ sb,
    const float* __restrict__ ra, const float* __restrict__ rb,
    const int* __restrict__ gt, float* __restrict__ out)
{
    __shared__ __align__(16) fp8_t As[BM * BKE];  // 16 KB
    __shared__ __align__(16) fp8_t Bs[BN * BKE];  // 16 KB

    const int tid  = threadIdx.x;
    const int wave = tid >> 6;
    const int lane = tid & 63;
    const int m0 = blockIdx.y * BM;
    const int n0 = blockIdx.x * BN;

    f32x4 acc[4][4] = {};

    const int fr = lane & 15;            // frag row (A) / frag col (B)
    const int q  = lane >> 4;            // quad: k-block (lane>>4)*32
    const int wm = (wave >> 1) * 64;
    const int wn = (wave & 1) * 64;

    const int srow = lane >> 3;
    const int sp   = lane & 7;

    for (int k0 = 0; k0 < DIM; k0 += BKE) {
        __syncthreads();   // prev iter's LDS reads done
        #pragma unroll
        for (int j = 0; j < 4; ++j) {          // A: 1024 chunks, 256/wave
            const int c0  = wave * 256 + j * 64;            // wave-uniform
            const int row = (c0 >> 3) + srow;
            const int gcx = sp ^ (row & 7);
            const fp8_t* ga = A + (size_t)(m0 + row) * DIM + k0 + gcx * 16;
            __builtin_amdgcn_global_load_lds(
                (const __attribute__((address_space(1))) void*)ga,
                (__attribute__((address_space(3))) void*)(As + c0 * 16),
                16, 0, 0);
        }
        #pragma unroll
        for (int j = 0; j < 4; ++j) {          // B: 1024 chunks, 256/wave
            const int c0  = wave * 256 + j * 64;
            const int row = (c0 >> 3) + srow;
            const int gcx = sp ^ (row & 7);
            const fp8_t* gb = B + (size_t)(n0 + row) * DIM + k0 + gcx * 16;
            __builtin_amdgcn_global_load_lds(
                (const __attribute__((address_space(1))) void*)gb,
                (__attribute__((address_space(3))) void*)(Bs + c0 * 16),
                16, 0, 0);
        }
        __syncthreads();   // staging complete

        // B fragments: 2x b128 per operand-col row (chunks 2q,2q+1)
        i32x8 bf[4];
        #pragma unroll
        for (int i = 0; i < 4; ++i) {
            const int br = wn + i * 16 + fr;
            const i32x4 lo =
                *(const i32x4*)(Bs + br * BKE + (((2 * q)     ^ (br & 7)) * 16));
            const i32x4 hi =
                *(const i32x4*)(Bs + br * BKE + (((2 * q + 1) ^ (br & 7)) * 16));
            bf[i] = __builtin_shufflevector(lo, hi, 0, 1, 2, 3, 4, 5, 6, 7);
        }

        // Per-mi: one A fragment (8 regs), then its 4 MFMAs. Peak live:
        // bf 32 + a 8 + acc 64 + addressing -> no spill window.
        #pragma unroll
        for (int mi = 0; mi < 4; ++mi) {
            const int ar = wm + mi * 16 + fr;
            const i32x4 lo =
                *(const i32x4*)(As + ar * BKE + (((2 * q)     ^ (ar & 7)) * 16));
            const i32x4 hi =
                *(const i32x4*)(As + ar * BKE + (((2 * q + 1) ^ (ar & 7)) * 16));
            const i32x8 a = __builtin_shufflevector(lo, hi, 0, 1, 2, 3, 4, 5, 6, 7);
            #pragma unroll
            for (int ni = 0; ni < 4; ++ni)
                acc[mi][ni] = __builtin_amdgcn_mfma_scale_f32_16x16x128_f8f6f4(
                    a, bf[ni], acc[mi][ni], 0, 0, 0, SC1, 0, SC1);
        }
    }

    // ---- fused epilogue: C/D col=lane&15, row=(lane>>4)*4+reg ----
    // (shape-determined layout, verified absmax=0 R10-R12)
    const int cq = lane & 15;
    const int rq = (lane >> 4) * 4;

    float cc[4];
    #pragma unroll
    for (int ni = 0; ni < 4; ++ni) {
        const int col = n0 + wn + ni * 16 + cq;
        cc[ni] = sb[col] - 2.0f * EPSV * rb[col];
    }

    float local = 0.0f;
    #pragma unroll
    for (int mi = 0; mi < 4; ++mi) {
        #pragma unroll
        for (int rr = 0; rr < 4; ++rr) {
            const int row = m0 + wm + mi * 16 + rq + rr;
            const float crr = sa[row] + 2.0f * EPSV * ra[row]
                            + (float)DIM * EPSV * EPSV;
            const int* gr = gt + (size_t)row * NROWS + n0 + wn + cq;
            int gvals[4];
            #pragma unroll
            for (int ni = 0; ni < 4; ++ni) gvals[ni] = gr[ni * 16];
            #pragma unroll
            for (int ni = 0; ni < 4; ++ni) {
                const float d2 = (crr + cc[ni]) - 2.0f * acc[mi][ni][rr];
                const float gf = (gvals[ni] != 0) ? 1.0f : 0.0f;
                float contrib = d2 - gf * d2;           // hinge==0 fast path
                if (__builtin_expect(d2 < 4.0f, 0)) {   // exact, never taken
                    const float d2c  = fmaxf(d2, 0.0f);
                    const float dist = sqrtf(d2c);
                    const float h    = fmaxf(MARGIN - dist, 0.0f);
                    contrib = (1.0f - gf) * d2c + gf * h * h;
                }
                local += contrib;
            }
        }
    }

    #pragma unroll
    for (int off = 32; off > 0; off >>= 1) local += __shfl_down(local, off);

    float* redp = (float*)As;   // reuse LDS for block reduction
    __syncthreads();
    if (lane == 0) redp[wave] = local;
    __syncthreads();
    if (tid == 0) {
        const float s = (redp[0] + redp[1]) + (redp[2] + redp[3]);
        atomicAdd(out, s * (1.0f / (4096.0f * 4096.0f)));
    }
}

// ---------------------------------------------------------------------------
extern "C" void kernel_launch(void* const* d_in, const int* in_sizes, int n_in,
                              void* d_out, int out_size, void* d_ws, size_t ws_size,
                              hipStream_t stream)
{
    const float* A  = (const float*)d_in[0];
    const float* B  = (const float*)d_in[1];
    const int*   gt = (const int*)d_in[2];
    float* out = (float*)d_out;

    char* ws = (char*)d_ws;
    const size_t NB8 = (size_t)NROWS * DIM;   // 3,145,728 B per fp8 matrix
    fp8_t* Af8 = (fp8_t*)(ws);
    fp8_t* Bf8 = (fp8_t*)(ws + NB8);
    float* sa = (float*)(ws + 2 * NB8);
    float* sb = (float*)(ws + 2 * NB8 + 16384);
    float* ra = (float*)(ws + 2 * NB8 + 32768);
    float* rb = (float*)(ws + 2 * NB8 + 49152);

    prologue_kernel<<<dim3(2048), 256, 0, stream>>>(
        A, B, Af8, Bf8, sa, sb, ra, rb, out);
    loss_kernel<<<dim3(NROWS / BN, NROWS / BM), 256, 0, stream>>>(
        Af8, Bf8, sa, sb, ra, rb, gt, out);
}

// Round 8
// 135.138 us; speedup vs baseline: 2.3636x; 1.2748x over previous
//
#include <hip/hip_runtime.h>
#include <hip/hip_bf16.h>
#include <stdint.h>
#include <stddef.h>

// ContrastiveLoss: N=4096, D=768.
// loss = mean_{ij} (1-g)*d2 + g*max(2-sqrt(d2),0)^2,
// d2 = sa[i]+sb[j]-2*dot(i,j)+2e-6*(ra[i]-rb[j])+768e-12 (clamped at 0).
// R6:  fp8 e4m3 GEMM, k-permuted layout, XOR-8 LDS, gt ballot-packed in
//      prologue, de-duplicated fused epilogue. 135.5 us — BEST.
// R7/R8 (FAILED): gt in K-loop -> __syncthreads drains in-flight vmem.
// R9 (138.1): gt direct in epilogue — burst tail costs ~7 us vs R6 pack.
// R10-R13 (FAILED 319/308/230/172): MX 16x16x128 ladder. Spill chased to 0
//      (per-mi operand streaming) but uncapped allocator takes 204 VGPR ->
//      2 waves/SIMD, Occupancy 9%, MfmaUtil 5.5%: latency-serialized, 87 us.
//      Plus persistent 1.57M LDS conflicts structural to b128 MX frag reads.
//      MX + 64-reg acc is misfit to plain-HIP 64x64/wave: capped=spill,
//      uncapped=occupancy collapse. MX abandoned per pre-committed criterion.
// R14 (this): R6 verbatim + bijective XCD swizzle on the loss grid
//      (1024 blocks % 8 == 0 -> simple form bijective; T1: L2 panel
//      sharing). Floor: fills 82 (harness) + prologue 16 (98.8 MB BW-floor)
//      + loss 33 (780 TF fp8) + overhead 5 = 136. At ~135 -> ROOFLINE.
// Lesson log: R4 32x32 frags = structural LDS conflict; R3 dbuf = spill;
//      WRITE_SIZE is the spill detector; R7/R8: never leave vmem in flight
//      across __syncthreads; R10-R13: 8-reg-operand MFMA + 64-reg acc
//      cannot be register-allocated viably in this structure.

#define NROWS 4096
#define DIM   768
#define BM    128
#define BN    128
#define BKE   128              // K elements per tile (128 B fp8 rows)
#define MARGIN 2.0f
#define EPSV   1e-6f

typedef float f32x4 __attribute__((ext_vector_type(4)));
typedef long  lng2  __attribute__((ext_vector_type(2)));
typedef unsigned long long u64;
typedef unsigned char fp8_t;

// Permutation of each 128-elem k-segment, baked into the fp8 global layout:
// element (kk,q,j) [kk=K32-window 0..3, q=quad 0..3, j=0..7] is stored at
// byte ((kk>>1)*4 + q)*16 + (kk&1)*8 + j. Both A and B use it => dot
// products are unchanged (same k-order on both operands).

// ---------------- prologue: prep (2048 blocks) + pack (8192 blocks) --------
__global__ __launch_bounds__(256) void prologue_kernel(
    const float* __restrict__ A, const float* __restrict__ B,
    const int* __restrict__ gt,
    fp8_t* __restrict__ Af8, fp8_t* __restrict__ Bf8,
    float* __restrict__ sa, float* __restrict__ sb,
    float* __restrict__ ra, float* __restrict__ rb,
    u64* __restrict__ gtp, float* __restrict__ out)
{
    const int tid  = threadIdx.x;
    const int wave = tid >> 6;
    const int lane = tid & 63;
    const int bx   = blockIdx.x;

    if (bx == 0 && tid == 0) out[0] = 0.0f;

    if (bx < 2048) {
        // ---- prep: fp8 cast (k-permuted) + exact fp32 row sums/sumsq ----
        const int isB  = bx >= 1024;
        const int row  = (bx & 1023) * 4 + wave;
        const float* X = isB ? B : A;
        fp8_t* Xb      = isB ? Bf8 : Af8;
        float* sdst    = isB ? sb : sa;
        float* rdst    = isB ? rb : ra;

        const float4* xr = (const float4*)(X + (size_t)row * DIM);
        unsigned int* xb = (unsigned int*)(Xb + (size_t)row * DIM);

        float sum = 0.0f, sq = 0.0f;
        #pragma unroll
        for (int jb = 0; jb < 3; ++jb) {
            float4 v = xr[lane + 64 * jb];
            int pk = 0;
            pk = __builtin_amdgcn_cvt_pk_fp8_f32(v.x, v.y, pk, false);
            pk = __builtin_amdgcn_cvt_pk_fp8_f32(v.z, v.w, pk, true);
            // permuted destination dword
            const int e4  = lane + 64 * jb;     // source dword idx in row
            const int seg = e4 >> 5;            // 128-elem segment
            const int e   = (e4 & 31) * 4;      // elem within segment
            const int kk  = e >> 5;
            const int q   = (e >> 3) & 3;
            const int jj  = e & 7;              // 0 or 4
            const int pos = ((kk >> 1) * 4 + q) * 16 + (kk & 1) * 8 + jj;
            xb[seg * 32 + (pos >> 2)] = (unsigned int)pk;
            sum += (v.x + v.y) + (v.z + v.w);
            sq  += v.x * v.x + v.y * v.y + v.z * v.z + v.w * v.w;
        }
        #pragma unroll
        for (int off = 32; off > 0; off >>= 1) {
            sum += __shfl_down(sum, off);
            sq  += __shfl_down(sq,  off);
        }
        if (lane == 0) { rdst[row] = sum; sdst[row] = sq; }
    } else {
        // ---- pack: gt int32 -> u64 bitmask per 64-col block ----
        const int wid = (bx - 2048) * 4 + wave;
        const size_t base = (size_t)wid * 8;
        int v[8];
        #pragma unroll
        for (int i = 0; i < 8; ++i)
            v[i] = gt[base * 64 + (size_t)i * 64 + lane];
        u64 mine = 0;
        #pragma unroll
        for (int i = 0; i < 8; ++i) {
            const u64 m = __ballot(v[i] != 0);
            if (lane == i) mine = m;
        }
        if (lane < 8) gtp[base + lane] = mine;
    }
}

// ---------------- fused GEMM + loss (fp8 e4m3, k-permuted layout) ----------
// 128x128 tile / 256 threads (4 waves x 64x64 of 4x4 16x16x32 fp8 MFMA).
// BKE=128 (128-B LDS rows), single-buffered 32 KB LDS, 2-barrier K-loop.
// Frag reads: b128 at chunk c = kk2*4 + q, slot (c ^ (row&7)) — R2's
// measured-conflict-free algebra. Each b128 = windows 2*kk2 (lo 8 B) and
// 2*kk2+1 (hi 8 B). 1D grid + bijective XCD swizzle (1024 % 8 == 0).
__global__ __launch_bounds__(256, 4) void loss_kernel(
    const fp8_t* __restrict__ A, const fp8_t* __restrict__ B,
    const float* __restrict__ sa, const float* __restrict__ sb,
    const float* __restrict__ ra, const float* __restrict__ rb,
    const uint2* __restrict__ gtp, float* __restrict__ out)
{
    __shared__ __align__(16) fp8_t As[BM * BKE];  // 16 KB
    __shared__ __align__(16) fp8_t Bs[BN * BKE];  // 16 KB

    const int tid  = threadIdx.x;
    const int wave = tid >> 6;
    const int lane = tid & 63;

    // XCD-aware bijective swizzle: 1024 tiles, 8 XCDs, 128 tiles each.
    const int bid = blockIdx.x;
    const int sw  = (bid & 7) * 128 + (bid >> 3);
    const int m0 = (sw >> 5) * BM;
    const int n0 = (sw & 31) * BN;

    f32x4 acc[4][4] = {};

    const int fr = lane & 15;            // frag row (A) / frag col (B)
    const int q  = lane >> 4;            // quad
    const int wm = (wave >> 1) * 64;
    const int wn = (wave & 1) * 64;

    // staging: chunk c (16 B) -> row c>>3, slot c&7; LDS slot p of row holds
    // global chunk p ^ (row&7)   [XOR-8 swizzle]
    const int srow = lane >> 3;
    const int sp   = lane & 7;

    for (int k0 = 0; k0 < DIM; k0 += BKE) {
        __syncthreads();   // prev iter's LDS reads done
        #pragma unroll
        for (int j = 0; j < 4; ++j) {          // A: 1024 chunks, 256/wave
            const int c0  = wave * 256 + j * 64;            // wave-uniform
            const int row = (c0 >> 3) + srow;
            const int gcx = sp ^ (row & 7);
            const fp8_t* ga = A + (size_t)(m0 + row) * DIM + k0 + gcx * 16;
            __builtin_amdgcn_global_load_lds(
                (const __attribute__((address_space(1))) void*)ga,
                (__attribute__((address_space(3))) void*)(As + c0 * 16),
                16, 0, 0);
        }
        #pragma unroll
        for (int j = 0; j < 4; ++j) {          // B: 1024 chunks, 256/wave
            const int c0  = wave * 256 + j * 64;
            const int row = (c0 >> 3) + srow;
            const int gcx = sp ^ (row & 7);
            const fp8_t* gb = B + (size_t)(n0 + row) * DIM + k0 + gcx * 16;
            __builtin_amdgcn_global_load_lds(
                (const __attribute__((address_space(1))) void*)gb,
                (__attribute__((address_space(3))) void*)(Bs + c0 * 16),
                16, 0, 0);
        }
        __syncthreads();   // staging complete

        #pragma unroll
        for (int kk2 = 0; kk2 < 2; ++kk2) {    // each step: 2 K=32 windows
            const int c = kk2 * 4 + q;         // consecutive chunk per quad
            lng2 ap[4], bp[4];
            #pragma unroll
            for (int i = 0; i < 4; ++i) {
                const int ar = wm + i * 16 + fr;
                const int br = wn + i * 16 + fr;
                ap[i] = *(const lng2*)(As + ar * BKE + ((c ^ (ar & 7)) * 16));
                bp[i] = *(const lng2*)(Bs + br * BKE + ((c ^ (br & 7)) * 16));
            }
            #pragma unroll
            for (int mi = 0; mi < 4; ++mi)
                #pragma unroll
                for (int ni = 0; ni < 4; ++ni)
                    acc[mi][ni] = __builtin_amdgcn_mfma_f32_16x16x32_fp8_fp8(
                        ap[mi][0], bp[ni][0], acc[mi][ni], 0, 0, 0);
            #pragma unroll
            for (int mi = 0; mi < 4; ++mi)
                #pragma unroll
                for (int ni = 0; ni < 4; ++ni)
                    acc[mi][ni] = __builtin_amdgcn_mfma_f32_16x16x32_fp8_fp8(
                        ap[mi][1], bp[ni][1], acc[mi][ni], 0, 0, 0);
        }
    }

    // ---- fused epilogue: C/D col=lane&15, row=(lane>>4)*4+reg ----
    // Single traversal; per-element rare exact branch (never taken for this
    // data: min d2 ~ 1250 >> 4) — no dup loop, no spill trigger.
    const int cq = lane & 15;
    const int rq = (lane >> 4) * 4;
    const int cb = (n0 + wn) >> 6;

    float cc[4];
    #pragma unroll
    for (int ni = 0; ni < 4; ++ni) {
        const int col = n0 + wn + ni * 16 + cq;
        cc[ni] = sb[col] - 2.0f * EPSV * rb[col];
    }

    float local = 0.0f;
    #pragma unroll
    for (int mi = 0; mi < 4; ++mi) {
        #pragma unroll
        for (int rr = 0; rr < 4; ++rr) {
            const int row = m0 + wm + mi * 16 + rq + rr;
            const float crr = sa[row] + 2.0f * EPSV * ra[row]
                            + (float)DIM * EPSV * EPSV;
            const uint2 w = gtp[(size_t)row * (NROWS / 64) + cb];
            #pragma unroll
            for (int ni = 0; ni < 4; ++ni) {
                const float d2 = (crr + cc[ni]) - 2.0f * acc[mi][ni][rr];
                const unsigned wd = (ni < 2) ? w.x : w.y;
                const float gf = (float)((wd >> (cq + (ni & 1) * 16)) & 1u);
                float contrib = d2 - gf * d2;           // hinge==0 fast path
                if (__builtin_expect(d2 < 4.0f, 0)) {   // exact, never taken
                    const float d2c  = fmaxf(d2, 0.0f);
                    const float dist = sqrtf(d2c);
                    const float h    = fmaxf(MARGIN - dist, 0.0f);
                    contrib = (1.0f - gf) * d2c + gf * h * h;
                }
                local += contrib;
            }
        }
    }

    #pragma unroll
    for (int off = 32; off > 0; off >>= 1) local += __shfl_down(local, off);

    float* redp = (float*)As;   // reuse LDS for block reduction
    __syncthreads();
    if (lane == 0) redp[wave] = local;
    __syncthreads();
    if (tid == 0) {
        const float s = (redp[0] + redp[1]) + (redp[2] + redp[3]);
        atomicAdd(out, s * (1.0f / (4096.0f * 4096.0f)));
    }
}

// ---------------------------------------------------------------------------
extern "C" void kernel_launch(void* const* d_in, const int* in_sizes, int n_in,
                              void* d_out, int out_size, void* d_ws, size_t ws_size,
                              hipStream_t stream)
{
    const float* A  = (const float*)d_in[0];
    const float* B  = (const float*)d_in[1];
    const int*   gt = (const int*)d_in[2];
    float* out = (float*)d_out;

    char* ws = (char*)d_ws;
    const size_t NB8 = (size_t)NROWS * DIM;   // 3,145,728 B per fp8 matrix
    fp8_t* Af8 = (fp8_t*)(ws);
    fp8_t* Bf8 = (fp8_t*)(ws + NB8);
    float* sa = (float*)(ws + 2 * NB8);
    float* sb = (float*)(ws + 2 * NB8 + 16384);
    float* ra = (float*)(ws + 2 * NB8 + 32768);
    float* rb = (float*)(ws + 2 * NB8 + 49152);
    u64* gtp  = (u64*)(ws + 2 * NB8 + 65536); // 2 MB

    prologue_kernel<<<dim3(10240), 256, 0, stream>>>(
        A, B, gt, Af8, Bf8, sa, sb, ra, rb, gtp, out);
    loss_kernel<<<dim3(1024), 256, 0, stream>>>(
        Af8, Bf8, sa, sb, ra, rb, (const uint2*)gtp, out);
}